// Round 1
// baseline (763.817 us; speedup 1.0000x reference)
//
#include <hip/hip_runtime.h>

// Problem constants (B=10240, D=512, M=8, L=3; K = M*D = 4096)
#define BB   10240
#define DD   512
#define MM   8
#define KTOT 4096

typedef __attribute__((ext_vector_type(8))) short  short8;
typedef __attribute__((ext_vector_type(4))) float  floatx4;

__device__ __forceinline__ unsigned short f2bf(float f) {
    union { float f; unsigned u; } v; v.f = f;
    unsigned r = v.u + 0x7fffu + ((v.u >> 16) & 1u);   // RNE
    return (unsigned short)(r >> 16);
}

// ---------------- Ws fp32 -> bf16 (all 3 layers at once) ----------------
__global__ void __launch_bounds__(256) cvt_ws_k(const float* __restrict__ s,
                                                unsigned short* __restrict__ d, int n8) {
    int i = blockIdx.x * 256 + threadIdx.x;
    if (i >= n8) return;
    const float4* sp = (const float4*)s + i * 2;
    float4 a = sp[0], b = sp[1];
    ushort4 o0 = make_ushort4(f2bf(a.x), f2bf(a.y), f2bf(a.z), f2bf(a.w));
    ushort4 o1 = make_ushort4(f2bf(b.x), f2bf(b.y), f2bf(b.z), f2bf(b.w));
    ushort4* dp = (ushort4*)d + i * 2;
    dp[0] = o0; dp[1] = o1;
}

// ---------------- fused layer GEMM ----------------
// C[b,i] = gW[b,i] * sum_k A'[b,k]*W'[k,i]  +  gb[b,i] * sum_m pb[b,m]*bsv[m,i]
// A'[b, m*512+j] = pW[b,m]*x[b,j]  (built during staging)
// W'[m*512+j, i] = Wbf[m,i,j]      (B^T tiles, bf16)
// Tile: BM=128, BN=64, BK=64 (one m per K-tile). 4 waves, wave = 64x32,
// mfma_f32_16x16x32_bf16, 4x2 acc tiles/wave. XOR-swizzled LDS (16B chunks).
__global__ void __launch_bounds__(256) gemm_layer(
    const float*  __restrict__ x,     // (B,512) fp32
    const unsigned short* __restrict__ Wbf, // (8,512,512) bf16
    const float*  __restrict__ pW,    // (B,8)
    const float*  __restrict__ pb,    // (B,8)
    const float*  __restrict__ bsv,   // (8,512)
    const float*  __restrict__ gW,    // (B,512)
    const float*  __restrict__ gb,    // (B,512)
    float* __restrict__ out)          // (B,512)
{
    __shared__ __align__(16) unsigned short As[128 * 64]; // row-major, XOR swizzle
    __shared__ __align__(16) unsigned short Bs[64 * 64];

    const int tid  = threadIdx.x;
    const int bn0  = blockIdx.x * 64;     // col tile (8 tiles)
    const int bm0  = blockIdx.y * 128;    // row tile (80 tiles)
    const int lane = tid & 63;
    const int w    = tid >> 6;
    const int wm   = w >> 1, wn = w & 1;
    const int ln16 = lane & 15, quad = lane >> 4;

    floatx4 acc[4][2] = {};

    for (int kt = 0; kt < 64; ++kt) {
        const int m  = kt >> 3;
        const int j0 = (kt & 7) * 64;

        // ---- stage A: 128 rows x 64 k, 8 chunks of 4 floats per thread ----
        #pragma unroll
        for (int it = 0; it < 8; ++it) {
            int c   = tid + 256 * it;
            int row = c >> 4;            // 0..127
            int j4  = c & 15;            // 4-elem chunk within row
            int gr  = bm0 + row;
            float4 xv = *(const float4*)(x + gr * DD + j0 + j4 * 4);
            float  sc = pW[gr * MM + m];
            ushort4 o = make_ushort4(f2bf(xv.x * sc), f2bf(xv.y * sc),
                                     f2bf(xv.z * sc), f2bf(xv.w * sc));
            int chunk = j4 >> 1;                       // 16B chunk 0..7
            int half  = j4 & 1;
            int phys  = chunk ^ (row & 7);
            *(ushort4*)(&As[row * 64 + phys * 8 + half * 4]) = o;
        }
        // ---- stage B: 64 i-rows x 64 k, 2 x 16B chunks per thread ----
        #pragma unroll
        for (int it = 0; it < 2; ++it) {
            int c   = tid + 256 * it;
            int row = c >> 3;            // i within tile, 0..63
            int cc  = c & 7;             // 16B chunk within row
            const unsigned short* gp = Wbf + m * (DD * DD) + (bn0 + row) * DD + j0 + cc * 8;
            float4 v = *(const float4*)gp;
            int phys = cc ^ (row & 7);
            *(float4*)(&Bs[row * 64 + phys * 8]) = v;
        }
        __syncthreads();

        // ---- MFMA: two k-steps of 32 ----
        #pragma unroll
        for (int ks = 0; ks < 2; ++ks) {
            short8 af[4], bfr[2];
            #pragma unroll
            for (int mt = 0; mt < 4; ++mt) {
                int row   = wm * 64 + mt * 16 + ln16;
                int chunk = ks * 4 + quad;
                int phys  = chunk ^ (row & 7);
                af[mt] = *(const short8*)(&As[row * 64 + phys * 8]);
            }
            #pragma unroll
            for (int nt = 0; nt < 2; ++nt) {
                int row   = wn * 32 + nt * 16 + ln16;
                int chunk = ks * 4 + quad;
                int phys  = chunk ^ (row & 7);
                bfr[nt] = *(const short8*)(&Bs[row * 64 + phys * 8]);
            }
            #pragma unroll
            for (int mt = 0; mt < 4; ++mt)
                #pragma unroll
                for (int nt = 0; nt < 2; ++nt)
                    acc[mt][nt] = __builtin_amdgcn_mfma_f32_16x16x32_bf16(
                        af[mt], bfr[nt], acc[mt][nt], 0, 0, 0);
        }
        __syncthreads();
    }

    // ---- epilogue: out = gW*acc + gb*(sum_m pb*bs) ----
    const int i0 = bn0 + wn * 32 + ln16;       // nt=0 column
    const int i1 = i0 + 16;                    // nt=1 column
    float bs0[8], bs1[8];
    #pragma unroll
    for (int mm2 = 0; mm2 < 8; ++mm2) {
        bs0[mm2] = bsv[mm2 * DD + i0];
        bs1[mm2] = bsv[mm2 * DD + i1];
    }
    #pragma unroll
    for (int mt = 0; mt < 4; ++mt) {
        #pragma unroll
        for (int r = 0; r < 4; ++r) {
            int b = bm0 + wm * 64 + mt * 16 + quad * 4 + r;
            float4 p0 = *(const float4*)(pb + b * MM);
            float4 p1 = *(const float4*)(pb + b * MM + 4);
            float bias0 = p0.x*bs0[0] + p0.y*bs0[1] + p0.z*bs0[2] + p0.w*bs0[3]
                        + p1.x*bs0[4] + p1.y*bs0[5] + p1.z*bs0[6] + p1.w*bs0[7];
            float bias1 = p0.x*bs1[0] + p0.y*bs1[1] + p0.z*bs1[2] + p0.w*bs1[3]
                        + p1.x*bs1[4] + p1.y*bs1[5] + p1.z*bs1[6] + p1.w*bs1[7];
            float g0  = gW[b * DD + i0], g1  = gW[b * DD + i1];
            float gg0 = gb[b * DD + i0], gg1 = gb[b * DD + i1];
            out[b * DD + i0] = g0 * acc[mt][0][r] + gg0 * bias0;
            out[b * DD + i1] = g1 * acc[mt][1][r] + gg1 * bias1;
        }
    }
}

// ---------------- rowwise LayerNorm (no affine) + ELU ----------------
// one wave per 512-wide row, 4 rows per block
__global__ void __launch_bounds__(256) ln_elu_k(const float* __restrict__ h,
                                                float* __restrict__ xo) {
    const int w    = threadIdx.x >> 6;
    const int lane = threadIdx.x & 63;
    const int row  = blockIdx.x * 4 + w;
    const float* hp = h + row * DD + lane * 8;
    float4 a = *(const float4*)hp;
    float4 b = *(const float4*)(hp + 4);
    float s = a.x + a.y + a.z + a.w + b.x + b.y + b.z + b.w;
    float q = a.x*a.x + a.y*a.y + a.z*a.z + a.w*a.w
            + b.x*b.x + b.y*b.y + b.z*b.z + b.w*b.w;
    #pragma unroll
    for (int off = 1; off < 64; off <<= 1) {
        s += __shfl_xor(s, off);
        q += __shfl_xor(q, off);
    }
    float mu   = s * (1.0f / 512.0f);
    float var  = q * (1.0f / 512.0f) - mu * mu;
    float rstd = rsqrtf(var + 1e-5f);
    float v[8] = {a.x, a.y, a.z, a.w, b.x, b.y, b.z, b.w};
    #pragma unroll
    for (int i = 0; i < 8; ++i) {
        float t = (v[i] - mu) * rstd;
        v[i] = t > 0.0f ? t : expm1f(t);
    }
    float* op = xo + row * DD + lane * 8;
    *(float4*)op       = make_float4(v[0], v[1], v[2], v[3]);
    *(float4*)(op + 4) = make_float4(v[4], v[5], v[6], v[7]);
}

extern "C" void kernel_launch(void* const* d_in, const int* in_sizes, int n_in,
                              void* d_out, int out_size, void* d_ws, size_t ws_size,
                              hipStream_t stream) {
    const float* x   = (const float*)d_in[0];   // (B,512)
    const float* Ws  = (const float*)d_in[1];   // (3,8,512,512)
    const float* bs  = (const float*)d_in[2];   // (3,8,512)
    const float* pWs = (const float*)d_in[3];   // (3,B,8)
    const float* pbs = (const float*)d_in[4];   // (3,B,8)
    const float* gWs = (const float*)d_in[5];   // (3,B,512,1)
    const float* gbs = (const float*)d_in[6];   // (3,B,512)
    float* out = (float*)d_out;

    // workspace: Wbf (12.58 MB) + xbuf (20.97 MB) = 32 MB
    unsigned short* Wbf = (unsigned short*)d_ws;
    float* xbuf = (float*)((char*)d_ws + (size_t)3 * MM * DD * DD * sizeof(unsigned short));

    const int wsl = MM * DD * DD;        // 2097152  (per-layer Ws elems)
    const int bsl = MM * DD;             // 4096
    const int pl  = BB * MM;             // 81920
    const int gl  = BB * DD;             // 5242880

    // Ws -> bf16 (3*8*512*512 / 8 elems per thread = 786432 threads)
    cvt_ws_k<<<3072, 256, 0, stream>>>(Ws, Wbf, 786432);

    dim3 gg(DD / 64, BB / 128);          // (8, 80)

    // layer 0: x -> xbuf (h0), LN in place
    gemm_layer<<<gg, 256, 0, stream>>>(x, Wbf, pWs, pbs, bs, gWs, gbs, xbuf);
    ln_elu_k<<<BB / 4, 256, 0, stream>>>(xbuf, xbuf);

    // layer 1: xbuf -> out (h1 scratch), LN out -> xbuf
    gemm_layer<<<gg, 256, 0, stream>>>(xbuf, Wbf + wsl, pWs + pl, pbs + pl,
                                       bs + bsl, gWs + gl, gbs + gl, out);
    ln_elu_k<<<BB / 4, 256, 0, stream>>>(out, xbuf);

    // layer 2: xbuf -> out (final, no LN)
    gemm_layer<<<gg, 256, 0, stream>>>(xbuf, Wbf + 2 * wsl, pWs + 2 * pl, pbs + 2 * pl,
                                       bs + 2 * bsl, gWs + 2 * gl, gbs + 2 * gl, out);
}

// Round 2
// 580.135 us; speedup vs baseline: 1.3166x; 1.3166x over previous
//
#include <hip/hip_runtime.h>
#include <math.h>

// Problem constants (B=10240, D=512, M=8, L=3)
#define BB   10240
#define DD   512
#define MM   8

typedef _Float16 h8 __attribute__((ext_vector_type(8)));
typedef float    f4 __attribute__((ext_vector_type(4)));

// async global->LDS DMA, 16 B per lane; LDS dst = wave-uniform base + lane*16
__device__ __forceinline__ void gload16(const void* g, void* l) {
    __builtin_amdgcn_global_load_lds(
        (__attribute__((address_space(1))) void*)(g),
        (__attribute__((address_space(3))) void*)(l), 16, 0, 0);
}

// ---------------- fp32 -> fp16 convert (8 elems/thread) ----------------
__global__ void __launch_bounds__(256) cvt_f32_f16(const float* __restrict__ s,
                                                   _Float16* __restrict__ d, int n8) {
    int i = blockIdx.x * 256 + threadIdx.x;
    if (i >= n8) return;
    const float4* sp = (const float4*)s + (size_t)i * 2;
    float4 a = sp[0], b = sp[1];
    h8 o = { (_Float16)a.x, (_Float16)a.y, (_Float16)a.z, (_Float16)a.w,
             (_Float16)b.x, (_Float16)b.y, (_Float16)b.z, (_Float16)b.w };
    *(h8*)(d + (size_t)i * 8) = o;
}

// ---------------- fused layer GEMM ----------------
// C[b,i] = gW[b,i] * sum_m pW[b,m] sum_j W[m,i,j] x[b,j]  +  gb[b,i]*sum_m pb[b,m]*bs[m,i]
// Tile BM=128, BN=64, BK=64. jc-outer (8), m-inner (8): A(x) tile staged once
// per jc via DMA, fragments held in regs across the m loop; pW scale applied
// in-register (v_pk_mul_f16). W tile (8 KB) DMA'd per (m,jc), double-buffered.
// XOR-swizzled LDS layout (16B chunk ^ row) -> 2-way max bank aliasing (free).
template <int HALF_OUT>
__global__ void __launch_bounds__(256) gemm_layer(
    const _Float16* __restrict__ xh,   // (B,512) fp16
    const _Float16* __restrict__ Wh,   // (8,512,512) fp16
    const float*  __restrict__ pW,     // (B,8)
    const float*  __restrict__ pb,     // (B,8)
    const float*  __restrict__ bsv,    // (8,512)
    const float*  __restrict__ gW,     // (B,512)
    const float*  __restrict__ gb,     // (B,512)
    float* __restrict__ outf,          // (B,512) fp32 (final layer)
    _Float16* __restrict__ outh)       // (B,512) fp16 (hidden layers)
{
    __shared__ __align__(16) _Float16 Abuf[2][128 * 64];  // 16 KB each
    __shared__ __align__(16) _Float16 Bbuf[2][64 * 64];   //  8 KB each

    const int tid  = threadIdx.x;
    const int lane = tid & 63;
    const int w    = tid >> 6;
    const int wm   = w >> 1, wn = w & 1;
    const int ln16 = lane & 15, quad = lane >> 4;
    const int bn0  = blockIdx.x * 64;
    const int bm0  = blockIdx.y * 128;

    // per-lane pW for this wave's 4 A-row groups, all 8 m, as fp16
    _Float16 pwh[4][8];
    #pragma unroll
    for (int mt = 0; mt < 4; ++mt) {
        const float* pp = pW + (size_t)(bm0 + wm * 64 + mt * 16 + ln16) * MM;
        float4 p0 = *(const float4*)pp;
        float4 p1 = *(const float4*)(pp + 4);
        pwh[mt][0] = (_Float16)p0.x; pwh[mt][1] = (_Float16)p0.y;
        pwh[mt][2] = (_Float16)p0.z; pwh[mt][3] = (_Float16)p0.w;
        pwh[mt][4] = (_Float16)p1.x; pwh[mt][5] = (_Float16)p1.y;
        pwh[mt][6] = (_Float16)p1.z; pwh[mt][7] = (_Float16)p1.w;
    }

    // --- DMA staging: contiguous per-wave 1 KB chunks; XOR swizzle applied
    //     on the GLOBAL side so LDS-phys chunk p of row r holds logical p^r. ---
    auto stageA = [&](int buf, int jc) {
        #pragma unroll
        for (int c = 0; c < 4; ++c) {
            int rbase   = w * 32 + c * 8;
            int row     = rbase + (lane >> 3);
            int logical = (lane & 7) ^ (row & 7);
            const _Float16* gp = xh + (size_t)(bm0 + row) * DD + jc * 64 + logical * 8;
            gload16(gp, &Abuf[buf][rbase * 64]);
        }
    };
    auto stageW = [&](int buf, int m, int jc) {
        #pragma unroll
        for (int c = 0; c < 2; ++c) {
            int rbase   = w * 16 + c * 8;
            int row     = rbase + (lane >> 3);
            int logical = (lane & 7) ^ (row & 7);
            const _Float16* gp = Wh + (size_t)m * (DD * DD)
                                    + (size_t)(bn0 + row) * DD + jc * 64 + logical * 8;
            gload16(gp, &Bbuf[buf][rbase * 64]);
        }
    };

    f4 acc[4][2] = {};
    h8 af[2][4];   // [ks][mt] A fragments, live across the m loop

    stageA(0, 0);
    stageW(0, 0, 0);

    for (int jc = 0; jc < 8; ++jc) {
        #pragma unroll
        for (int mi = 0; mi < 8; ++mi) {
            __syncthreads();   // drains prior DMA (vmcnt(0) before s_barrier)

            // prefetch next tile into alternate buffers
            if (mi == 7) {
                if (jc < 7) {
                    stageW(0, 0, jc + 1);
                    stageA((jc + 1) & 1, jc + 1);
                }
            } else {
                stageW((mi + 1) & 1, mi + 1, jc);
            }

            if (mi == 0) {
                #pragma unroll
                for (int ks = 0; ks < 2; ++ks)
                    #pragma unroll
                    for (int mt = 0; mt < 4; ++mt) {
                        int row  = wm * 64 + mt * 16 + ln16;
                        int phys = (ks * 4 + quad) ^ (row & 7);
                        af[ks][mt] = *(const h8*)&Abuf[jc & 1][row * 64 + phys * 8];
                    }
            }

            h8 bfr[2][2];  // [ks][nt]
            #pragma unroll
            for (int ks = 0; ks < 2; ++ks)
                #pragma unroll
                for (int nt = 0; nt < 2; ++nt) {
                    int row  = wn * 32 + nt * 16 + ln16;
                    int phys = (ks * 4 + quad) ^ (row & 7);
                    bfr[ks][nt] = *(const h8*)&Bbuf[mi & 1][row * 64 + phys * 8];
                }

            #pragma unroll
            for (int ks = 0; ks < 2; ++ks)
                #pragma unroll
                for (int mt = 0; mt < 4; ++mt) {
                    h8 as = af[ks][mt] * pwh[mt][mi];   // v_pk_mul_f16 x4
                    #pragma unroll
                    for (int nt = 0; nt < 2; ++nt)
                        acc[mt][nt] = __builtin_amdgcn_mfma_f32_16x16x32_f16(
                            as, bfr[ks][nt], acc[mt][nt], 0, 0, 0);
                }
        }
    }

    // ---- epilogue: out = gW*acc + gb*(sum_m pb*bs) ----
    const int i0 = bn0 + wn * 32 + ln16;
    const int i1 = i0 + 16;
    float bs0[8], bs1[8];
    #pragma unroll
    for (int m2 = 0; m2 < 8; ++m2) {
        bs0[m2] = bsv[m2 * DD + i0];
        bs1[m2] = bsv[m2 * DD + i1];
    }
    #pragma unroll
    for (int mt = 0; mt < 4; ++mt) {
        #pragma unroll
        for (int r = 0; r < 4; ++r) {
            int b = bm0 + wm * 64 + mt * 16 + quad * 4 + r;
            float4 p0 = *(const float4*)(pb + (size_t)b * MM);
            float4 p1 = *(const float4*)(pb + (size_t)b * MM + 4);
            float bias0 = p0.x*bs0[0] + p0.y*bs0[1] + p0.z*bs0[2] + p0.w*bs0[3]
                        + p1.x*bs0[4] + p1.y*bs0[5] + p1.z*bs0[6] + p1.w*bs0[7];
            float bias1 = p0.x*bs1[0] + p0.y*bs1[1] + p0.z*bs1[2] + p0.w*bs1[3]
                        + p1.x*bs1[4] + p1.y*bs1[5] + p1.z*bs1[6] + p1.w*bs1[7];
            float v0 = gW[(size_t)b * DD + i0] * acc[mt][0][r] + gb[(size_t)b * DD + i0] * bias0;
            float v1 = gW[(size_t)b * DD + i1] * acc[mt][1][r] + gb[(size_t)b * DD + i1] * bias1;
            if (HALF_OUT) {
                outh[(size_t)b * DD + i0] = (_Float16)v0;
                outh[(size_t)b * DD + i1] = (_Float16)v1;
            } else {
                outf[(size_t)b * DD + i0] = v0;
                outf[(size_t)b * DD + i1] = v1;
            }
        }
    }
}

// ---------------- LayerNorm (no affine) + ELU, fp16 in/out ----------------
__global__ void __launch_bounds__(256) ln_elu_h(const _Float16* __restrict__ h,
                                                _Float16* __restrict__ xo) {
    const int w    = threadIdx.x >> 6;
    const int lane = threadIdx.x & 63;
    const int row  = blockIdx.x * 4 + w;
    h8 v = *(const h8*)(h + (size_t)row * DD + lane * 8);
    float f[8], s = 0.f, q = 0.f;
    #pragma unroll
    for (int i = 0; i < 8; ++i) { f[i] = (float)v[i]; s += f[i]; q += f[i] * f[i]; }
    #pragma unroll
    for (int off = 1; off < 64; off <<= 1) {
        s += __shfl_xor(s, off);
        q += __shfl_xor(q, off);
    }
    float mu   = s * (1.0f / 512.0f);
    float var  = q * (1.0f / 512.0f) - mu * mu;
    float rstd = rsqrtf(var + 1e-5f);
    h8 o;
    #pragma unroll
    for (int i = 0; i < 8; ++i) {
        float t = (f[i] - mu) * rstd;
        t = t > 0.0f ? t : expm1f(t);
        o[i] = (_Float16)t;
    }
    *(h8*)(xo + (size_t)row * DD + lane * 8) = o;
}

extern "C" void kernel_launch(void* const* d_in, const int* in_sizes, int n_in,
                              void* d_out, int out_size, void* d_ws, size_t ws_size,
                              hipStream_t stream) {
    const float* x   = (const float*)d_in[0];   // (B,512)
    const float* Ws  = (const float*)d_in[1];   // (3,8,512,512)
    const float* bs  = (const float*)d_in[2];   // (3,8,512)
    const float* pWs = (const float*)d_in[3];   // (3,B,8)
    const float* pbs = (const float*)d_in[4];   // (3,B,8)
    const float* gWs = (const float*)d_in[5];   // (3,B,512,1)
    const float* gbs = (const float*)d_in[6];   // (3,B,512)
    float* out = (float*)d_out;

    // workspace: Wh 12.58 MB + xh 10.49 MB + hh 10.49 MB = 32 MiB exactly
    _Float16* Wh = (_Float16*)d_ws;
    _Float16* xh = Wh + (size_t)3 * MM * DD * DD;
    _Float16* hh = xh + (size_t)BB * DD;

    const int wsl = MM * DD * DD;        // per-layer W elems
    const int bsl = MM * DD;
    const int pl  = BB * MM;
    const int gl  = BB * DD;

    cvt_f32_f16<<<3072, 256, 0, stream>>>(Ws, Wh, 786432);   // 3*8*512*512/8
    cvt_f32_f16<<<2560, 256, 0, stream>>>(x, xh, 655360);    // B*512/8

    dim3 gg(DD / 64, BB / 128);          // (8, 80)

    // layer 0
    gemm_layer<1><<<gg, 256, 0, stream>>>(xh, Wh, pWs, pbs, bs, gWs, gbs,
                                          nullptr, hh);
    ln_elu_h<<<BB / 4, 256, 0, stream>>>(hh, xh);
    // layer 1
    gemm_layer<1><<<gg, 256, 0, stream>>>(xh, Wh + wsl, pWs + pl, pbs + pl,
                                          bs + bsl, gWs + gl, gbs + gl,
                                          nullptr, hh);
    ln_elu_h<<<BB / 4, 256, 0, stream>>>(hh, xh);
    // layer 2 (no LN, fp32 out)
    gemm_layer<0><<<gg, 256, 0, stream>>>(xh, Wh + 2 * wsl, pWs + 2 * pl,
                                          pbs + 2 * pl, bs + 2 * bsl,
                                          gWs + 2 * gl, gbs + 2 * gl,
                                          out, nullptr);
}